// Round 1
// baseline (511.080 us; speedup 1.0000x reference)
//
#include <hip/hip_runtime.h>
#include <math.h>

// Problem constants (B,T,E,H fixed by setup_inputs).
constexpr int B_ = 8, T_ = 2048, E_ = 1024, H_ = 64;
constexpr long BTH = (long)B_ * T_ * H_;   // 1,048,576 elements per q/k/v buffer

// ====================================================================
// Kernel 1: fused QKV projection.  x:[BT,E] @ W{k,q,v}:[E,H] -> [BT,H]
// q is pre-scaled by H^-0.5 so attention needs no extra scale.
// 512 blocks x 256 threads; 32 rows/block; K staged in 64-chunks.
// LDS: xs stride 65 -> bank = (row+kk)%32, conflict-free scalar reads.
// ====================================================================
constexpr int RT = 32;   // rows per block
constexpr int KC = 64;   // K chunk

__global__ __launch_bounds__(256, 2) void qkv_proj_k(
    const float* __restrict__ x,  const float* __restrict__ Wk,
    const float* __restrict__ Wq, const float* __restrict__ Wv,
    float* __restrict__ kO, float* __restrict__ qO, float* __restrict__ vO)
{
    __shared__ float xs[RT][65];
    __shared__ float ws[3][KC * H_];   // [mat][kk*64 + h], stride 64 (16B-aligned f4 reads)

    const int t  = threadIdx.x;
    const int r0 = blockIdx.x * RT;
    const int rq = t >> 4;   // 0..15 -> 2 rows each
    const int cq = t & 15;   // 0..15 -> 4 cols each

    float acc[3][2][4];
    #pragma unroll
    for (int m = 0; m < 3; m++)
        #pragma unroll
        for (int i = 0; i < 2; i++)
            #pragma unroll
            for (int j = 0; j < 4; j++) acc[m][i][j] = 0.f;

    for (int e0 = 0; e0 < E_; e0 += KC) {
        __syncthreads();   // protect previous iteration's LDS reads
        // stage x chunk: 32x64 floats = 512 float4, 2 per thread, coalesced
        #pragma unroll
        for (int p = 0; p < 2; ++p) {
            int idx = t + p * 256;
            int row = idx >> 4;
            int c4  = (idx & 15) * 4;
            float4 xv = *(const float4*)(x + (size_t)(r0 + row) * E_ + e0 + c4);
            xs[row][c4 + 0] = xv.x; xs[row][c4 + 1] = xv.y;
            xs[row][c4 + 2] = xv.z; xs[row][c4 + 3] = xv.w;
        }
        // stage W chunks: each 64x64 contiguous (full H rows), straight f4 copy
        #pragma unroll
        for (int m = 0; m < 3; m++) {
            const float* Wm = (m == 0 ? Wk : (m == 1 ? Wq : Wv)) + (size_t)e0 * H_;
            #pragma unroll
            for (int p = 0; p < 4; p++) {
                int idx = (t + p * 256) * 4;
                *(float4*)(&ws[m][idx]) = *(const float4*)(Wm + idx);
            }
        }
        __syncthreads();

        #pragma unroll 4
        for (int kk = 0; kk < KC; ++kk) {
            float xv0 = xs[rq * 2 + 0][kk];
            float xv1 = xs[rq * 2 + 1][kk];
            #pragma unroll
            for (int m = 0; m < 3; m++) {
                float4 wv = *(const float4*)(&ws[m][kk * H_ + cq * 4]);
                acc[m][0][0] = fmaf(xv0, wv.x, acc[m][0][0]);
                acc[m][0][1] = fmaf(xv0, wv.y, acc[m][0][1]);
                acc[m][0][2] = fmaf(xv0, wv.z, acc[m][0][2]);
                acc[m][0][3] = fmaf(xv0, wv.w, acc[m][0][3]);
                acc[m][1][0] = fmaf(xv1, wv.x, acc[m][1][0]);
                acc[m][1][1] = fmaf(xv1, wv.y, acc[m][1][1]);
                acc[m][1][2] = fmaf(xv1, wv.z, acc[m][1][2]);
                acc[m][1][3] = fmaf(xv1, wv.w, acc[m][1][3]);
            }
        }
    }

    const float qs = 0.125f;   // H^-0.5 = 1/8
    #pragma unroll
    for (int m = 0; m < 3; m++) {
        float* op = (m == 0 ? kO : (m == 1 ? qO : vO));
        float  s  = (m == 1) ? qs : 1.0f;
        #pragma unroll
        for (int i = 0; i < 2; i++) {
            size_t r = (size_t)(r0 + rq * 2 + i);
            float4 o = make_float4(acc[m][i][0] * s, acc[m][i][1] * s,
                                   acc[m][i][2] * s, acc[m][i][3] * s);
            *(float4*)(op + r * H_ + cq * 4) = o;
        }
    }
}

// ====================================================================
// Kernel 2: flash-style causal attention, fp32.
// Pair-balanced schedule: block (b, pair) handles q-tiles {pair, 63-pair}
// -> every block does exactly (pair+1) + (64-pair) = 65 k-tile iterations.
// Grid: 8 * 32 = 256 blocks x 256 threads.
// Per-thread: 4 scores (sqi = t>>3, ki = (t&7)*4+j);
//             8 O elements (oqi = t>>3, h = (t&7)*8 + j).
// LDS strides: Q/K = 68 (f4-aligned, bank-spread), V = 64, S = 33.
// ====================================================================
constexpr int TQ = 32, TK = 32;
constexpr int NQT = T_ / TQ;   // 64

__global__ __launch_bounds__(256, 1) void attn_k(
    const float* __restrict__ q, const float* __restrict__ k,
    const float* __restrict__ v, float* __restrict__ out)
{
    __shared__ float Qs[TQ][68];
    __shared__ float Ks[TK][68];
    __shared__ float Vs[TK][H_];
    __shared__ float Ss[TQ][33];
    __shared__ float mS[TQ], lS[TQ], aS[TQ];

    const int t    = threadIdx.x;
    const int b    = blockIdx.x >> 5;
    const int pair = blockIdx.x & 31;
    const int oqi  = t >> 3;   // 0..31
    const int ohg  = t & 7;    // 0..7
    const int sqi  = t >> 3;
    const int ski4 = t & 7;

    #pragma unroll 1
    for (int half = 0; half < 2; ++half) {
        const int qt = half ? (NQT - 1 - pair) : pair;
        const size_t qbase = (size_t)b * T_ + (size_t)qt * TQ;

        __syncthreads();   // previous half's lS reads / LDS reuse
        // stage Q tile (32x64), f4-aligned into stride-68 LDS
        #pragma unroll
        for (int p = 0; p < 2; p++) {
            int idx = t + p * 256;
            int row = idx >> 4;
            int c4  = (idx & 15) * 4;
            *(float4*)(&Qs[row][c4]) = *(const float4*)(q + (qbase + row) * H_ + c4);
        }
        if (t < TQ) { mS[t] = -1e30f; lS[t] = 0.f; }

        float o[8];
        #pragma unroll
        for (int j = 0; j < 8; j++) o[j] = 0.f;

        for (int kt = 0; kt <= qt; ++kt) {
            __syncthreads();   // previous iter's Ks/Vs/Ss reads done
            const size_t kbase = (size_t)b * T_ + (size_t)kt * TK;
            #pragma unroll
            for (int p = 0; p < 2; p++) {
                int idx = t + p * 256;
                int row = idx >> 4;
                int c4  = (idx & 15) * 4;
                *(float4*)(&Ks[row][c4]) = *(const float4*)(k + (kbase + row) * H_ + c4);
                *(float4*)(&Vs[row][c4]) = *(const float4*)(v + (kbase + row) * H_ + c4);
            }
            __syncthreads();

            // ---- scores: S[sqi][ski4*4+j] = q_row . k_row ----
            float s4[4] = {0.f, 0.f, 0.f, 0.f};
            #pragma unroll 4
            for (int h = 0; h < H_; h += 4) {
                float4 qv = *(const float4*)(&Qs[sqi][h]);
                #pragma unroll
                for (int j = 0; j < 4; j++) {
                    float4 kv = *(const float4*)(&Ks[ski4 * 4 + j][h]);
                    s4[j] = fmaf(qv.x, kv.x,
                            fmaf(qv.y, kv.y,
                            fmaf(qv.z, kv.z,
                            fmaf(qv.w, kv.w, s4[j]))));
                }
            }
            if (kt == qt) {   // diagonal tile: mask strictly-upper triangle
                #pragma unroll
                for (int j = 0; j < 4; j++)
                    if (ski4 * 4 + j > sqi) s4[j] = -1e30f;
            }
            #pragma unroll
            for (int j = 0; j < 4; j++) Ss[sqi][ski4 * 4 + j] = s4[j];
            __syncthreads();

            // ---- online softmax update (one thread per q-row) ----
            if (t < TQ) {
                float mo = mS[t];
                float rm = mo;
                #pragma unroll 8
                for (int kj = 0; kj < TK; kj++) rm = fmaxf(rm, Ss[t][kj]);
                float a = __expf(mo - rm);
                float sum = 0.f;
                #pragma unroll 8
                for (int kj = 0; kj < TK; kj++) {
                    float p = __expf(Ss[t][kj] - rm);
                    Ss[t][kj] = p;
                    sum += p;
                }
                lS[t] = lS[t] * a + sum;
                mS[t] = rm;
                aS[t] = a;
            }
            __syncthreads();

            // ---- O = O*alpha + P @ V ----
            float al = aS[oqi];
            #pragma unroll
            for (int j = 0; j < 8; j++) o[j] *= al;
            #pragma unroll 8
            for (int ki = 0; ki < TK; ki++) {
                float  p  = Ss[oqi][ki];
                float4 v0 = *(const float4*)(&Vs[ki][ohg * 8]);
                float4 v1 = *(const float4*)(&Vs[ki][ohg * 8 + 4]);
                o[0] = fmaf(p, v0.x, o[0]); o[1] = fmaf(p, v0.y, o[1]);
                o[2] = fmaf(p, v0.z, o[2]); o[3] = fmaf(p, v0.w, o[3]);
                o[4] = fmaf(p, v1.x, o[4]); o[5] = fmaf(p, v1.y, o[5]);
                o[6] = fmaf(p, v1.z, o[6]); o[7] = fmaf(p, v1.w, o[7]);
            }
        }

        // ---- epilogue: out = O / l ---- (lS written before last barrier)
        float inv = 1.0f / lS[oqi];
        float4 o0 = make_float4(o[0] * inv, o[1] * inv, o[2] * inv, o[3] * inv);
        float4 o1 = make_float4(o[4] * inv, o[5] * inv, o[6] * inv, o[7] * inv);
        float* op = out + (qbase + oqi) * H_ + ohg * 8;
        *(float4*)op       = o0;
        *(float4*)(op + 4) = o1;
    }
}

// ====================================================================
extern "C" void kernel_launch(void* const* d_in, const int* in_sizes, int n_in,
                              void* d_out, int out_size, void* d_ws, size_t ws_size,
                              hipStream_t stream)
{
    // setup_inputs order: x, Wk, Wq, Wv (all float32)
    const float* x  = (const float*)d_in[0];
    const float* Wk = (const float*)d_in[1];
    const float* Wq = (const float*)d_in[2];
    const float* Wv = (const float*)d_in[3];

    // workspace: k | q | v, each BTH floats (12 MB total)
    float* kbuf = (float*)d_ws;
    float* qbuf = kbuf + BTH;
    float* vbuf = kbuf + 2 * BTH;
    float* outp = (float*)d_out;

    qkv_proj_k<<<(B_ * T_) / RT, 256, 0, stream>>>(x, Wk, Wq, Wv, kbuf, qbuf, vbuf);
    attn_k<<<B_ * (NQT / 2), 256, 0, stream>>>(qbuf, kbuf, vbuf, outp);
}

// Round 2
// 243.343 us; speedup vs baseline: 2.1002x; 2.1002x over previous
//
#include <hip/hip_runtime.h>
#include <math.h>

// Problem constants (B,T,E,H fixed by setup_inputs).
constexpr int B_ = 8, T_ = 2048, E_ = 1024, H_ = 64;
constexpr long BT = (long)B_ * T_;   // 16384 rows

typedef __attribute__((ext_vector_type(8))) short bf16x8;   // 8 bf16 (4 VGPRs)
typedef __attribute__((ext_vector_type(4))) float f32x4;    // MFMA 16x16 acc

__device__ inline unsigned short bf16_rne(float f) {
    union { float f; unsigned u; } v; v.f = f;
    unsigned u = v.u + (0x7FFFu + ((v.u >> 16) & 1u));
    return (unsigned short)(u >> 16);
}
__device__ inline unsigned pack_bf16x2(float lo, float hi) {
    return (unsigned)bf16_rne(lo) | ((unsigned)bf16_rne(hi) << 16);
}

// ====================================================================
// Kernel 1: fused QKV projection (fp32 VALU compute, unchanged core).
// New epilogue: bf16 outputs. q pre-scaled by H^-0.5 * log2(e) (base-2
// softmax trick). v written TRANSPOSED+PERMUTED: Vt[b][h][t'] where
// within each 32-block t' = 2*(i%16) + i/16 — matches the attention
// kernel's P-in-LDS packing so PV b-frags are contiguous 16B reads.
// ====================================================================
constexpr int RT = 32;   // rows per block
constexpr int KC = 64;   // K chunk

__global__ __launch_bounds__(256, 2) void qkv_proj_k(
    const float* __restrict__ x,  const float* __restrict__ Wk,
    const float* __restrict__ Wq, const float* __restrict__ Wv,
    unsigned short* __restrict__ kO, unsigned short* __restrict__ qO,
    unsigned short* __restrict__ vtO)
{
    __shared__ float xs[RT][65];
    __shared__ float ws[3][KC * H_];

    const int t  = threadIdx.x;
    const int r0 = blockIdx.x * RT;
    const int rq = t >> 4;
    const int cq = t & 15;

    float acc[3][2][4];
    #pragma unroll
    for (int m = 0; m < 3; m++)
        #pragma unroll
        for (int i = 0; i < 2; i++)
            #pragma unroll
            for (int j = 0; j < 4; j++) acc[m][i][j] = 0.f;

    for (int e0 = 0; e0 < E_; e0 += KC) {
        __syncthreads();
        #pragma unroll
        for (int p = 0; p < 2; ++p) {
            int idx = t + p * 256;
            int row = idx >> 4;
            int c4  = (idx & 15) * 4;
            float4 xv = *(const float4*)(x + (size_t)(r0 + row) * E_ + e0 + c4);
            xs[row][c4 + 0] = xv.x; xs[row][c4 + 1] = xv.y;
            xs[row][c4 + 2] = xv.z; xs[row][c4 + 3] = xv.w;
        }
        #pragma unroll
        for (int m = 0; m < 3; m++) {
            const float* Wm = (m == 0 ? Wk : (m == 1 ? Wq : Wv)) + (size_t)e0 * H_;
            #pragma unroll
            for (int p = 0; p < 4; p++) {
                int idx = (t + p * 256) * 4;
                *(float4*)(&ws[m][idx]) = *(const float4*)(Wm + idx);
            }
        }
        __syncthreads();

        #pragma unroll 4
        for (int kk = 0; kk < KC; ++kk) {
            float xv0 = xs[rq * 2 + 0][kk];
            float xv1 = xs[rq * 2 + 1][kk];
            #pragma unroll
            for (int m = 0; m < 3; m++) {
                float4 wv = *(const float4*)(&ws[m][kk * H_ + cq * 4]);
                acc[m][0][0] = fmaf(xv0, wv.x, acc[m][0][0]);
                acc[m][0][1] = fmaf(xv0, wv.y, acc[m][0][1]);
                acc[m][0][2] = fmaf(xv0, wv.z, acc[m][0][2]);
                acc[m][0][3] = fmaf(xv0, wv.w, acc[m][0][3]);
                acc[m][1][0] = fmaf(xv1, wv.x, acc[m][1][0]);
                acc[m][1][1] = fmaf(xv1, wv.y, acc[m][1][1]);
                acc[m][1][2] = fmaf(xv1, wv.z, acc[m][1][2]);
                acc[m][1][3] = fmaf(xv1, wv.w, acc[m][1][3]);
            }
        }
    }

    const float qs = 0.18033688011112042f;   // (1/8) * log2(e)
    #pragma unroll
    for (int i = 0; i < 2; i++) {
        const int row = r0 + rq * 2 + i;
        // k (bf16)
        unsigned ka = pack_bf16x2(acc[0][i][0], acc[0][i][1]);
        unsigned kb = pack_bf16x2(acc[0][i][2], acc[0][i][3]);
        *(uint2*)(kO + (size_t)row * H_ + cq * 4) = make_uint2(ka, kb);
        // q (bf16, pre-scaled for exp2-softmax)
        unsigned qa = pack_bf16x2(acc[1][i][0] * qs, acc[1][i][1] * qs);
        unsigned qb = pack_bf16x2(acc[1][i][2] * qs, acc[1][i][3] * qs);
        *(uint2*)(qO + (size_t)row * H_ + cq * 4) = make_uint2(qa, qb);
        // v -> Vt[b][h][t'] with per-32-block key permutation
        const int b   = row >> 11;
        const int tl  = row & 2047;
        const int kt  = tl >> 5;
        const int i32 = tl & 31;
        const int tp  = (kt << 5) | ((i32 & 15) << 1) | (i32 >> 4);
        #pragma unroll
        for (int j = 0; j < 4; j++)
            vtO[((size_t)b * H_ + cq * 4 + j) * T_ + tp] = bf16_rne(acc[2][i][j]);
    }
}

// ====================================================================
// Kernel 2: MFMA flash attention, barrier-free k-loop.
// Block = 4 waves, ONE 16-row q-tile, split-K across waves (kt = w mod 4).
// Per k-tile (TK=32) per wave: 4 MFMA QK^T + in-register online softmax
// (shfl_xor row reduce within quads) + P LDS round-trip (C-layout ->
// A-layout, key-permuted pos=2*(key%16)+key/16) + 4 MFMA PV.
// Q/K/Vt fragments loaded straight from global (16B/lane, L2-resident).
// End-of-block flash merge of the 4 wave states via LDS.
// Grid: 1024 blocks (b in low 3 bits -> XCD spread; qt swizzled
// light/heavy alternating for load balance). 4 blocks/CU -> 16 waves/CU.
// ====================================================================
__global__ __launch_bounds__(256, 4) void attn_mfma(
    const unsigned short* __restrict__ q,   // bf16 [B][T][H], pre-scaled
    const unsigned short* __restrict__ k,   // bf16 [B][T][H]
    const unsigned short* __restrict__ vt,  // bf16 [B][H][T] permuted
    float* __restrict__ out)
{
    __shared__ unsigned short Pl[4][16 * 40];   // per-wave P, row stride 40 bf16 (80B, 16B-aligned)
    __shared__ float Ot[4][16][68];             // merge buffer (+4 pad: 2-way max)
    __shared__ float mlW[4][2][16];             // per-wave m,l per row

    const int t    = threadIdx.x;
    const int w    = t >> 6;
    const int l    = t & 63;
    const int l16  = l & 15;
    const int quad = l >> 4;

    const int b    = blockIdx.x & 7;
    const int qidx = blockIdx.x >> 3;                                  // 0..127
    const int qt   = (qidx & 1) ? (127 - (qidx >> 1)) : (qidx >> 1);   // light/heavy mix
    const int t0   = qt * 16;
    const int nk   = (t0 + 15) / 32 + 1;   // causal k-tiles of 32

    // Q A-frags (resident whole loop): aq[c][j] = Q[t0+l16][c*32 + quad*8 + j]
    const size_t qoff = ((size_t)b * T_ + t0 + l16) * H_ + quad * 8;
    bf16x8 aq0 = *(const bf16x8*)(q + qoff);
    bf16x8 aq1 = *(const bf16x8*)(q + qoff + 32);

    f32x4 o[4];
    #pragma unroll
    for (int g = 0; g < 4; g++) o[g] = (f32x4){0.f, 0.f, 0.f, 0.f};
    float m[4], lsum[4];
    #pragma unroll
    for (int r = 0; r < 4; r++) { m[r] = -3.0e38f; lsum[r] = 0.f; }

    const unsigned short* kbp = k  + (size_t)b * T_ * H_;
    const unsigned short* vbp = vt + (size_t)b * H_ * T_;
    unsigned short* Pw = &Pl[w][0];

    for (int kt = w; kt < nk; kt += 4) {
        const int kbase = kt * 32;
        // K B-frags: bk[g][c][j] = K[kbase+g*16+l16][c*32+quad*8+j]
        const unsigned short* kp = kbp + (size_t)(kbase + l16) * H_ + quad * 8;
        bf16x8 bk00 = *(const bf16x8*)(kp);
        bf16x8 bk01 = *(const bf16x8*)(kp + 32);
        bf16x8 bk10 = *(const bf16x8*)(kp + 16 * H_);
        bf16x8 bk11 = *(const bf16x8*)(kp + 16 * H_ + 32);
        // V B-frags (permuted positions match P packing)
        const unsigned short* vp = vbp + (size_t)l16 * T_ + kbase + quad * 8;
        bf16x8 bv0 = *(const bf16x8*)(vp);
        bf16x8 bv1 = *(const bf16x8*)(vp + 16 * T_);
        bf16x8 bv2 = *(const bf16x8*)(vp + 32 * T_);
        bf16x8 bv3 = *(const bf16x8*)(vp + 48 * T_);

        // S = Q K^T : s[g] cols = keys kbase+g*16+l16, rows = t0+quad*4+r
        f32x4 s0 = (f32x4){0.f, 0.f, 0.f, 0.f};
        f32x4 s1 = (f32x4){0.f, 0.f, 0.f, 0.f};
        s0 = __builtin_amdgcn_mfma_f32_16x16x32_bf16(aq0, bk00, s0, 0, 0, 0);
        s0 = __builtin_amdgcn_mfma_f32_16x16x32_bf16(aq1, bk01, s0, 0, 0, 0);
        s1 = __builtin_amdgcn_mfma_f32_16x16x32_bf16(aq0, bk10, s1, 0, 0, 0);
        s1 = __builtin_amdgcn_mfma_f32_16x16x32_bf16(aq1, bk11, s1, 0, 0, 0);

        if (kbase + 31 > t0) {   // diagonal tile only
            const int rowb = t0 + quad * 4;
            #pragma unroll
            for (int r = 0; r < 4; r++) {
                if (kbase + l16 > rowb + r)      s0[r] = -3.0e38f;
                if (kbase + 16 + l16 > rowb + r) s1[r] = -3.0e38f;
            }
        }

        // online softmax (base-2; scale folded into q)
        float alpha[4];
        #pragma unroll
        for (int r = 0; r < 4; r++) {
            float cm = fmaxf(s0[r], s1[r]);
            cm = fmaxf(cm, __shfl_xor(cm, 1));
            cm = fmaxf(cm, __shfl_xor(cm, 2));
            cm = fmaxf(cm, __shfl_xor(cm, 4));
            cm = fmaxf(cm, __shfl_xor(cm, 8));
            float nm = fmaxf(m[r], cm);
            float a  = exp2f(m[r] - nm);
            float p0 = exp2f(s0[r] - nm);
            float p1 = exp2f(s1[r] - nm);
            float rs = p0 + p1;
            rs += __shfl_xor(rs, 1);
            rs += __shfl_xor(rs, 2);
            rs += __shfl_xor(rs, 4);
            rs += __shfl_xor(rs, 8);
            lsum[r] = lsum[r] * a + rs;
            m[r] = nm; alpha[r] = a;
            s0[r] = p0; s1[r] = p1;   // reuse as P
        }
        #pragma unroll
        for (int g = 0; g < 4; g++)
            #pragma unroll
            for (int r = 0; r < 4; r++) o[g][r] *= alpha[r];

        // P C-layout -> LDS (packed key pairs at pos 2*l16, 2*l16+1)
        #pragma unroll
        for (int r = 0; r < 4; r++) {
            unsigned pk = pack_bf16x2(s0[r], s1[r]);
            *(unsigned*)(Pw + (quad * 4 + r) * 40 + 2 * l16) = pk;
        }
        asm volatile("s_waitcnt lgkmcnt(0)" ::: "memory");   // wave-local; no __syncthreads
        // A-frag read: ap[j] = P[q=l16][pos=quad*8+j]  (16B contiguous)
        bf16x8 ap = *(const bf16x8*)(Pw + l16 * 40 + quad * 8);

        // O += P V  (K=32, permuted key order consistent on both sides)
        o[0] = __builtin_amdgcn_mfma_f32_16x16x32_bf16(ap, bv0, o[0], 0, 0, 0);
        o[1] = __builtin_amdgcn_mfma_f32_16x16x32_bf16(ap, bv1, o[1], 0, 0, 0);
        o[2] = __builtin_amdgcn_mfma_f32_16x16x32_bf16(ap, bv2, o[2], 0, 0, 0);
        o[3] = __builtin_amdgcn_mfma_f32_16x16x32_bf16(ap, bv3, o[3], 0, 0, 0);
    }

    // ---- merge the 4 split-K wave states ----
    if (l16 == 0) {
        #pragma unroll
        for (int r = 0; r < 4; r++) {
            mlW[w][0][quad * 4 + r] = m[r];
            mlW[w][1][quad * 4 + r] = lsum[r];
        }
    }
    __syncthreads();

    float scl[4], Linv[4];
    #pragma unroll
    for (int r = 0; r < 4; r++) {
        const int row = quad * 4 + r;
        float m0 = mlW[0][0][row], m1 = mlW[1][0][row];
        float m2 = mlW[2][0][row], m3 = mlW[3][0][row];
        float M  = fmaxf(fmaxf(m0, m1), fmaxf(m2, m3));
        float L  = mlW[0][1][row] * exp2f(m0 - M) + mlW[1][1][row] * exp2f(m1 - M)
                 + mlW[2][1][row] * exp2f(m2 - M) + mlW[3][1][row] * exp2f(m3 - M);
        scl[r]  = exp2f(m[r] - M);
        Linv[r] = 1.0f / L;
    }
    #pragma unroll
    for (int g = 0; g < 4; g++)
        #pragma unroll
        for (int r = 0; r < 4; r++)
            Ot[w][quad * 4 + r][g * 16 + l16] = o[g][r] * scl[r];
    __syncthreads();

    if (w == 0) {
        #pragma unroll
        for (int g = 0; g < 4; g++) {
            #pragma unroll
            for (int r = 0; r < 4; r++) {
                const int row = quad * 4 + r, col = g * 16 + l16;
                float sv = Ot[0][row][col] + Ot[1][row][col]
                         + Ot[2][row][col] + Ot[3][row][col];
                out[((size_t)b * T_ + t0 + row) * H_ + col] = sv * Linv[r];
            }
        }
    }
}

// ====================================================================
extern "C" void kernel_launch(void* const* d_in, const int* in_sizes, int n_in,
                              void* d_out, int out_size, void* d_ws, size_t ws_size,
                              hipStream_t stream)
{
    const float* x  = (const float*)d_in[0];
    const float* Wk = (const float*)d_in[1];
    const float* Wq = (const float*)d_in[2];
    const float* Wv = (const float*)d_in[3];

    // workspace: k | q | vt  (bf16, 2 MB each = 6 MB)
    unsigned short* kbuf  = (unsigned short*)d_ws;
    unsigned short* qbuf  = kbuf + BT * H_;
    unsigned short* vtbuf = qbuf + BT * H_;
    float* outp = (float*)d_out;

    qkv_proj_k<<<(B_ * T_) / RT, 256, 0, stream>>>(x, Wk, Wq, Wv, kbuf, qbuf, vtbuf);
    attn_mfma<<<B_ * 128, 256, 0, stream>>>(qbuf, kbuf, vtbuf, outp);
}

// Round 3
// 176.322 us; speedup vs baseline: 2.8986x; 1.3801x over previous
//
#include <hip/hip_runtime.h>
#include <math.h>

// Problem constants (B,T,E,H fixed by setup_inputs).
constexpr int B_ = 8, T_ = 2048, E_ = 1024, H_ = 64;
constexpr long BT = (long)B_ * T_;   // 16384 rows

typedef __attribute__((ext_vector_type(8))) short bf16x8;   // 8 bf16 (4 VGPRs)
typedef __attribute__((ext_vector_type(4))) float f32x4;    // MFMA 16x16 acc

__device__ inline unsigned short bf16_rne(float f) {
    union { float f; unsigned u; } v; v.f = f;
    unsigned u = v.u + (0x7FFFu + ((v.u >> 16) & 1u));
    return (unsigned short)(u >> 16);
}
__device__ inline unsigned pack_bf16x2(float lo, float hi) {
    return (unsigned)bf16_rne(lo) | ((unsigned)bf16_rne(hi) << 16);
}

constexpr float QS = 0.18033688011112042f;   // H^-0.5 * log2(e), folded into Wq

// ====================================================================
// Kernel 0: build B-frag-ready transposed bf16 weight buffer.
// Wt elem[(tile*64 + lane)*8 + j] = W[kc*32 + quad*8 + j][n]
//   tile = kc*12 + n_tile, lane = quad*16 + l16, n = n_tile*16 + l16.
// A wave's b-frag for (kc,n_tile) is then 64 lanes x 16B contiguous (1KB).
// n in [0,64) -> Wk, [64,128) -> Wq (pre-scaled), [128,192) -> Wv.
// 24576 threads total = 96 blocks x 256.
// ====================================================================
__global__ __launch_bounds__(256) void wt_build_k(
    const float* __restrict__ Wk, const float* __restrict__ Wq,
    const float* __restrict__ Wv, unsigned short* __restrict__ Wt)
{
    const int d    = blockIdx.x * 256 + threadIdx.x;   // 0..24575
    const int tile = d >> 6;
    const int lq   = d & 63;
    const int quad = lq >> 4;
    const int l16  = lq & 15;
    const int kc   = tile / 12;
    const int nt   = tile - kc * 12;
    const int n    = nt * 16 + l16;

    const float* src; int col; float s = 1.0f;
    if (n < 64)       { src = Wk; col = n; }
    else if (n < 128) { src = Wq; col = n - 64; s = QS; }
    else              { src = Wv; col = n - 128; }

    const int kk0 = kc * 32 + quad * 8;
    const float* sp = src + (size_t)kk0 * H_ + col;
    unsigned p[4];
    #pragma unroll
    for (int jj = 0; jj < 4; jj++)
        p[jj] = pack_bf16x2(sp[(2 * jj) * H_] * s, sp[(2 * jj + 1) * H_] * s);
    *(uint4*)(Wt + (size_t)d * 8) = make_uint4(p[0], p[1], p[2], p[3]);
}

// ====================================================================
// Kernel 1: MFMA QKV projection. [16384x1024]@[1024x192] bf16->bf16.
// No LDS, no barriers. 512 blocks x 4 waves; wave = 16 rows x 6 n-tiles.
// A-frags: direct fp32 global loads (32B/lane) + in-register RNE->bf16.
// B-frags: contiguous 16B/lane loads from L2-resident Wt.
// kc-loop hand-pipelined: prefetch kc+1 (wrap-around keeps addrs in
// bounds) so 8 vmem stay in flight across the 6-MFMA body.
// Epilogue: k/q row-major bf16; v transposed+permuted Vt[b][h][t'].
// ====================================================================
__global__ __launch_bounds__(256) void qkv_mfma_k(
    const float* __restrict__ x, const unsigned short* __restrict__ Wt,
    unsigned short* __restrict__ kO, unsigned short* __restrict__ qO,
    unsigned short* __restrict__ vtO)
{
    const int t    = threadIdx.x;
    const int w    = t >> 6;
    const int l    = t & 63;
    const int l16  = l & 15;
    const int quad = l >> 4;
    const int rg   = w >> 1;   // row-group (0,1)
    const int nh   = w & 1;    // N-half (0,1)
    const int row0 = blockIdx.x * 32 + rg * 16;

    const float* xp = x + (size_t)(row0 + l16) * E_ + quad * 8;
    const unsigned short* wp = Wt + (size_t)(nh * 6) * 512 + (size_t)l * 8;

    f32x4 acc[6];
    #pragma unroll
    for (int n = 0; n < 6; n++) acc[n] = (f32x4){0.f, 0.f, 0.f, 0.f};

    // prefetch kc=0
    float4 a0 = *(const float4*)(xp);
    float4 a1 = *(const float4*)(xp + 4);
    bf16x8 bf[6];
    #pragma unroll
    for (int n = 0; n < 6; n++) bf[n] = *(const bf16x8*)(wp + (size_t)n * 512);

    for (int kc = 0; kc < 32; ++kc) {
        const int kn = (kc + 1) & 31;   // wrap: always in-bounds, last iter harmless
        float4 na0 = *(const float4*)(xp + kn * 32);
        float4 na1 = *(const float4*)(xp + kn * 32 + 4);
        bf16x8 nb[6];
        #pragma unroll
        for (int n = 0; n < 6; n++)
            nb[n] = *(const bf16x8*)(wp + (size_t)(kn * 12 + n) * 512);

        union { bf16x8 v; unsigned u[4]; } av;
        av.u[0] = pack_bf16x2(a0.x, a0.y);
        av.u[1] = pack_bf16x2(a0.z, a0.w);
        av.u[2] = pack_bf16x2(a1.x, a1.y);
        av.u[3] = pack_bf16x2(a1.z, a1.w);

        #pragma unroll
        for (int n = 0; n < 6; n++)
            acc[n] = __builtin_amdgcn_mfma_f32_16x16x32_bf16(av.v, bf[n], acc[n], 0, 0, 0);

        a0 = na0; a1 = na1;
        #pragma unroll
        for (int n = 0; n < 6; n++) bf[n] = nb[n];
    }

    // ---- epilogue: D[row=quad*4+r][col=l16] per n-tile ----
    #pragma unroll
    for (int n = 0; n < 6; n++) {
        const int gn = nh * 6 + n;
        const int hb = gn * 16 + l16;   // global output column 0..191
        if (gn < 4) {                   // k-range (cols 0..63)
            #pragma unroll
            for (int r = 0; r < 4; r++) {
                const int row = row0 + quad * 4 + r;
                kO[(size_t)row * H_ + hb] = bf16_rne(acc[n][r]);
            }
        } else if (gn < 8) {            // q-range (cols 64..127), already scaled
            #pragma unroll
            for (int r = 0; r < 4; r++) {
                const int row = row0 + quad * 4 + r;
                qO[(size_t)row * H_ + (hb - 64)] = bf16_rne(acc[n][r]);
            }
        } else {                        // v-range -> Vt[b][h][t'] permuted
            const int h = hb - 128;
            #pragma unroll
            for (int r = 0; r < 4; r++) {
                const int row = row0 + quad * 4 + r;
                const int b   = row >> 11;
                const int tl  = row & 2047;
                const int ktb = tl >> 5;
                const int i32 = tl & 31;
                const int tp  = (ktb << 5) | ((i32 & 15) << 1) | (i32 >> 4);
                vtO[((size_t)b * H_ + h) * T_ + tp] = bf16_rne(acc[n][r]);
            }
        }
    }
}

// ====================================================================
// Kernel 2: MFMA flash attention, barrier-free k-loop. (unchanged, R2)
// ====================================================================
__global__ __launch_bounds__(256, 4) void attn_mfma(
    const unsigned short* __restrict__ q,   // bf16 [B][T][H], pre-scaled
    const unsigned short* __restrict__ k,   // bf16 [B][T][H]
    const unsigned short* __restrict__ vt,  // bf16 [B][H][T] permuted
    float* __restrict__ out)
{
    __shared__ unsigned short Pl[4][16 * 40];
    __shared__ float Ot[4][16][68];
    __shared__ float mlW[4][2][16];

    const int t    = threadIdx.x;
    const int w    = t >> 6;
    const int l    = t & 63;
    const int l16  = l & 15;
    const int quad = l >> 4;

    const int b    = blockIdx.x & 7;
    const int qidx = blockIdx.x >> 3;
    const int qt   = (qidx & 1) ? (127 - (qidx >> 1)) : (qidx >> 1);
    const int t0   = qt * 16;
    const int nk   = (t0 + 15) / 32 + 1;

    const size_t qoff = ((size_t)b * T_ + t0 + l16) * H_ + quad * 8;
    bf16x8 aq0 = *(const bf16x8*)(q + qoff);
    bf16x8 aq1 = *(const bf16x8*)(q + qoff + 32);

    f32x4 o[4];
    #pragma unroll
    for (int g = 0; g < 4; g++) o[g] = (f32x4){0.f, 0.f, 0.f, 0.f};
    float m[4], lsum[4];
    #pragma unroll
    for (int r = 0; r < 4; r++) { m[r] = -3.0e38f; lsum[r] = 0.f; }

    const unsigned short* kbp = k  + (size_t)b * T_ * H_;
    const unsigned short* vbp = vt + (size_t)b * H_ * T_;
    unsigned short* Pw = &Pl[w][0];

    for (int kt = w; kt < nk; kt += 4) {
        const int kbase = kt * 32;
        const unsigned short* kp = kbp + (size_t)(kbase + l16) * H_ + quad * 8;
        bf16x8 bk00 = *(const bf16x8*)(kp);
        bf16x8 bk01 = *(const bf16x8*)(kp + 32);
        bf16x8 bk10 = *(const bf16x8*)(kp + 16 * H_);
        bf16x8 bk11 = *(const bf16x8*)(kp + 16 * H_ + 32);
        const unsigned short* vp = vbp + (size_t)l16 * T_ + kbase + quad * 8;
        bf16x8 bv0 = *(const bf16x8*)(vp);
        bf16x8 bv1 = *(const bf16x8*)(vp + 16 * T_);
        bf16x8 bv2 = *(const bf16x8*)(vp + 32 * T_);
        bf16x8 bv3 = *(const bf16x8*)(vp + 48 * T_);

        f32x4 s0 = (f32x4){0.f, 0.f, 0.f, 0.f};
        f32x4 s1 = (f32x4){0.f, 0.f, 0.f, 0.f};
        s0 = __builtin_amdgcn_mfma_f32_16x16x32_bf16(aq0, bk00, s0, 0, 0, 0);
        s0 = __builtin_amdgcn_mfma_f32_16x16x32_bf16(aq1, bk01, s0, 0, 0, 0);
        s1 = __builtin_amdgcn_mfma_f32_16x16x32_bf16(aq0, bk10, s1, 0, 0, 0);
        s1 = __builtin_amdgcn_mfma_f32_16x16x32_bf16(aq1, bk11, s1, 0, 0, 0);

        if (kbase + 31 > t0) {
            const int rowb = t0 + quad * 4;
            #pragma unroll
            for (int r = 0; r < 4; r++) {
                if (kbase + l16 > rowb + r)      s0[r] = -3.0e38f;
                if (kbase + 16 + l16 > rowb + r) s1[r] = -3.0e38f;
            }
        }

        float alpha[4];
        #pragma unroll
        for (int r = 0; r < 4; r++) {
            float cm = fmaxf(s0[r], s1[r]);
            cm = fmaxf(cm, __shfl_xor(cm, 1));
            cm = fmaxf(cm, __shfl_xor(cm, 2));
            cm = fmaxf(cm, __shfl_xor(cm, 4));
            cm = fmaxf(cm, __shfl_xor(cm, 8));
            float nm = fmaxf(m[r], cm);
            float a  = exp2f(m[r] - nm);
            float p0 = exp2f(s0[r] - nm);
            float p1 = exp2f(s1[r] - nm);
            float rs = p0 + p1;
            rs += __shfl_xor(rs, 1);
            rs += __shfl_xor(rs, 2);
            rs += __shfl_xor(rs, 4);
            rs += __shfl_xor(rs, 8);
            lsum[r] = lsum[r] * a + rs;
            m[r] = nm; alpha[r] = a;
            s0[r] = p0; s1[r] = p1;
        }
        #pragma unroll
        for (int g = 0; g < 4; g++)
            #pragma unroll
            for (int r = 0; r < 4; r++) o[g][r] *= alpha[r];

        #pragma unroll
        for (int r = 0; r < 4; r++) {
            unsigned pk = pack_bf16x2(s0[r], s1[r]);
            *(unsigned*)(Pw + (quad * 4 + r) * 40 + 2 * l16) = pk;
        }
        asm volatile("s_waitcnt lgkmcnt(0)" ::: "memory");
        bf16x8 ap = *(const bf16x8*)(Pw + l16 * 40 + quad * 8);

        o[0] = __builtin_amdgcn_mfma_f32_16x16x32_bf16(ap, bv0, o[0], 0, 0, 0);
        o[1] = __builtin_amdgcn_mfma_f32_16x16x32_bf16(ap, bv1, o[1], 0, 0, 0);
        o[2] = __builtin_amdgcn_mfma_f32_16x16x32_bf16(ap, bv2, o[2], 0, 0, 0);
        o[3] = __builtin_amdgcn_mfma_f32_16x16x32_bf16(ap, bv3, o[3], 0, 0, 0);
    }

    if (l16 == 0) {
        #pragma unroll
        for (int r = 0; r < 4; r++) {
            mlW[w][0][quad * 4 + r] = m[r];
            mlW[w][1][quad * 4 + r] = lsum[r];
        }
    }
    __syncthreads();

    float scl[4], Linv[4];
    #pragma unroll
    for (int r = 0; r < 4; r++) {
        const int row = quad * 4 + r;
        float m0 = mlW[0][0][row], m1 = mlW[1][0][row];
        float m2 = mlW[2][0][row], m3 = mlW[3][0][row];
        float M  = fmaxf(fmaxf(m0, m1), fmaxf(m2, m3));
        float L  = mlW[0][1][row] * exp2f(m0 - M) + mlW[1][1][row] * exp2f(m1 - M)
                 + mlW[2][1][row] * exp2f(m2 - M) + mlW[3][1][row] * exp2f(m3 - M);
        scl[r]  = exp2f(m[r] - M);
        Linv[r] = 1.0f / L;
    }
    #pragma unroll
    for (int g = 0; g < 4; g++)
        #pragma unroll
        for (int r = 0; r < 4; r++)
            Ot[w][quad * 4 + r][g * 16 + l16] = o[g][r] * scl[r];
    __syncthreads();

    if (w == 0) {
        #pragma unroll
        for (int g = 0; g < 4; g++) {
            #pragma unroll
            for (int r = 0; r < 4; r++) {
                const int row = quad * 4 + r, col = g * 16 + l16;
                float sv = Ot[0][row][col] + Ot[1][row][col]
                         + Ot[2][row][col] + Ot[3][row][col];
                out[((size_t)b * T_ + t0 + row) * H_ + col] = sv * Linv[r];
            }
        }
    }
}

// ====================================================================
extern "C" void kernel_launch(void* const* d_in, const int* in_sizes, int n_in,
                              void* d_out, int out_size, void* d_ws, size_t ws_size,
                              hipStream_t stream)
{
    const float* x  = (const float*)d_in[0];
    const float* Wk = (const float*)d_in[1];
    const float* Wq = (const float*)d_in[2];
    const float* Wv = (const float*)d_in[3];

    // workspace: Wt (384KB) | k | q | vt (bf16, 2MB each)
    unsigned short* wt    = (unsigned short*)d_ws;
    unsigned short* kbuf  = wt + 24576 * 8;
    unsigned short* qbuf  = kbuf + BT * H_;
    unsigned short* vtbuf = qbuf + BT * H_;
    float* outp = (float*)d_out;

    wt_build_k<<<96, 256, 0, stream>>>(Wk, Wq, Wv, wt);
    qkv_mfma_k<<<(B_ * T_) / 32, 256, 0, stream>>>(x, wt, kbuf, qbuf, vtbuf);
    attn_mfma<<<B_ * 128, 256, 0, stream>>>(qbuf, kbuf, vtbuf, outp);
}